// Round 9
// baseline (122.713 us; speedup 1.0000x reference)
//
#include <hip/hip_runtime.h>
#include <hip/hip_bf16.h>
#include <stdint.h>

typedef __bf16 bf16x8 __attribute__((ext_vector_type(8)));
typedef float f32x4 __attribute__((ext_vector_type(4)));

constexpr int Bn = 8, Ln = 4096, Dn = 512, Hn = 512;
constexpr int Mrows = Bn * Ln;                  // 32768
constexpr int CHUNK = 64, NCHUNK = Ln / CHUNK;  // 64 chunks of 64
constexpr int LNBLK = Mrows / 4;                // 8192: 1 row per wave, 4 waves/block

// ---------------------------------------------------------------- pre: LN (wave-per-row) + weight prep
__global__ __launch_bounds__(256) void pre_kernel(
    const float* __restrict__ x, const float* __restrict__ gamma,
    const float* __restrict__ beta,
    const float* __restrict__ W_B, const float* __restrict__ W_C,
    const float* __restrict__ W_out, const float* __restrict__ b_B,
    const float* __restrict__ b_C,
    __hip_bfloat16* __restrict__ xn,
    __hip_bfloat16* __restrict__ WbcT, __hip_bfloat16* __restrict__ WoT,
    float* __restrict__ bbc)
{
    int t = threadIdx.x;
    if (blockIdx.x >= LNBLK) {                 // prep role: 2048 blocks
        int id = (blockIdx.x - LNBLK) * 256 + t;   // covers 1024*512
        {
            int n = id >> 9, k = id & 511;
            float wv = (n < Hn) ? W_B[k * Hn + n] : W_C[k * Hn + (n - Hn)];
            WbcT[id] = __float2bfloat16(wv);   // WbcT[n][k] = W[k][n]
        }
        if (id < Hn * Hn) {
            int n = id >> 9, k = id & 511;
            WoT[id] = __float2bfloat16(W_out[k * Hn + n]);
        }
        if (id < 2 * Hn) bbc[id] = (id < Hn) ? b_B[id] : b_C[id - Hn];
        return;
    }
    // LN role: one row per wave, no LDS, shfl_xor butterfly
    int wid = t >> 6, lane = t & 63;
    int blk = blockIdx.x;
    int row = (blk & 7) * Ln + (blk >> 3) * 4 + wid;   // XCD-aligned: blk%8 = batch
    const float4* xr = reinterpret_cast<const float4*>(x + (size_t)row * Dn);
    float4 pa = xr[lane], pb = xr[lane + 64];
    float s  = pa.x + pa.y + pa.z + pa.w + pb.x + pb.y + pb.z + pb.w;
    float s2 = pa.x * pa.x + pa.y * pa.y + pa.z * pa.z + pa.w * pa.w
             + pb.x * pb.x + pb.y * pb.y + pb.z * pb.z + pb.w * pb.w;
    #pragma unroll
    for (int off = 1; off < 64; off <<= 1) {
        s  += __shfl_xor(s, off);
        s2 += __shfl_xor(s2, off);
    }
    float mu = s * (1.0f / Dn);
    float var = s2 * (1.0f / Dn) - mu * mu;
    float inv = rsqrtf(var + 1e-5f);
    const float4* g4 = reinterpret_cast<const float4*>(gamma);
    const float4* b4 = reinterpret_cast<const float4*>(beta);
    float4 ga = g4[lane], gb = g4[lane + 64];
    float4 ba = b4[lane], bb = b4[lane + 64];
    __hip_bfloat16 o[8];
    o[0] = __float2bfloat16((pa.x - mu) * inv * ga.x + ba.x);
    o[1] = __float2bfloat16((pa.y - mu) * inv * ga.y + ba.y);
    o[2] = __float2bfloat16((pa.z - mu) * inv * ga.z + ba.z);
    o[3] = __float2bfloat16((pa.w - mu) * inv * ga.w + ba.w);
    o[4] = __float2bfloat16((pb.x - mu) * inv * gb.x + bb.x);
    o[5] = __float2bfloat16((pb.y - mu) * inv * gb.y + bb.y);
    o[6] = __float2bfloat16((pb.z - mu) * inv * gb.z + bb.z);
    o[7] = __float2bfloat16((pb.w - mu) * inv * gb.w + bb.w);
    ushort4* xo = reinterpret_cast<ushort4*>(xn + (size_t)row * Dn);
    xo[lane]      = *reinterpret_cast<ushort4*>(&o[0]);
    xo[lane + 64] = *reinterpret_cast<ushort4*>(&o[4]);
}

// ---------------------------------------------------------------- BK=32 high-occupancy GEMM
// C[M][NT] = A[M][512] * BT[NT][512]^T + bias.  BM=BN=128, BK=32, 4 waves,
// dbuf LDS 32KB -> 4 blocks/CU (16 waves/CU, 2x the BK=64 version's TLP).
// 16 K-tiles, 1 phase each: RD(8x b128) | BAR | STAGE(kt+2) + 16 MFMA | gate | BAR.
// Swizzle: slot' = slot ^ (row&3), both sides (write via pre-swizzled global col).
// Per-acc K order = kt ascending == previous kernels -> bit-identical output.
template <int NT, bool OUT_BF16, bool WRITE_S>
__global__ __launch_bounds__(256, 4) void gemm32_kernel(
    const __hip_bfloat16* __restrict__ A,
    const __hip_bfloat16* __restrict__ BT,
    const float* __restrict__ bias,
    void* __restrict__ Cout,
    const float* __restrict__ Av, float* __restrict__ Sout)
{
    constexpr int K = 512, NKT = 16;           // 16 K-tiles of 32
    extern __shared__ unsigned short lds[];    // 16384 shorts = 32 KB

    int nwg = gridDim.x, bid = blockIdx.x;
    int bswz = (bid & 7) * (nwg >> 3) + (bid >> 3);   // XCD swizzle (nwg%8==0)
    constexpr int NBN = NT / 128;
    int bm = bswz / NBN, bnb = bswz % NBN;
    int row0 = bm * 128, col0 = bnb * 128;

    int tid = threadIdx.x;
    int w = tid >> 6, l = tid & 63;
    int rl = l & 15, qg = l >> 4;

    // staging lane map: GLDS covers 16 rows x 32 cols; lane -> row l>>2, slot l&3
    int srow = l >> 2, sslot = l & 3;
    int scol = (sslot ^ (srow & 3)) * 8;       // pre-swizzled global elem offset
    const __hip_bfloat16* gA = A  + (size_t)(row0 + w * 32 + srow) * K + scol;
    const __hip_bfloat16* gB = BT + (size_t)(col0 + w * 32 + srow) * K + scol;

    // LDS shorts: buf*8192 | A:0 B:4096 | row*32 + slot'*8
#define GLDS(src, dst) __builtin_amdgcn_global_load_lds( \
        (const __attribute__((address_space(1))) void*)(const void*)(src), \
        (__attribute__((address_space(3))) void*)(void*)(dst), 16, 0, 0)
#define STA(b, kt, s) GLDS(gA + (size_t)(s) * 16 * K + (kt) * 32, \
        &lds[(b) * 8192 + w * 1024 + (s) * 512])
#define STB(b, kt, s) GLDS(gB + (size_t)(s) * 16 * K + (kt) * 32, \
        &lds[(b) * 8192 + 4096 + w * 1024 + (s) * 512])
#define STAGE(b, kt) { STA(b, kt, 0); STA(b, kt, 1); STB(b, kt, 0); STB(b, kt, 1); }
#define BARRIER { asm volatile("" ::: "memory"); __builtin_amdgcn_s_barrier(); \
                  asm volatile("" ::: "memory"); }
#define VMCNT(n) asm volatile("s_waitcnt vmcnt(" #n ")" ::: "memory")

    int s0 = (qg ^ (rl & 3)) * 8;              // read slot elems (swizzled)
    int arow = (w >> 1) * 64 + rl;             // wave M-half base row + lane row
    int brow = (w & 1) * 64 + rl;              // wave N-half base row + lane row

    f32x4 acc[4][4] = {};
    bf16x8 af[4], bfr[4];

#define RDALL(b) { \
        _Pragma("unroll") for (int i2 = 0; i2 < 4; ++i2) \
            af[i2]  = *(const bf16x8*)&lds[(b) * 8192 + (arow + i2 * 16) * 32 + s0]; \
        _Pragma("unroll") for (int j2 = 0; j2 < 4; ++j2) \
            bfr[j2] = *(const bf16x8*)&lds[(b) * 8192 + 4096 + (brow + j2 * 16) * 32 + s0]; }
#define MMALL { __builtin_amdgcn_s_setprio(1); \
        _Pragma("unroll") for (int mi = 0; mi < 4; ++mi) \
        _Pragma("unroll") for (int ni = 0; ni < 4; ++ni) \
            acc[mi][ni] = __builtin_amdgcn_mfma_f32_16x16x32_bf16( \
                af[mi], bfr[ni], acc[mi][ni], 0, 0, 0); \
        __builtin_amdgcn_s_setprio(0); }

    // prologue: kt0 -> buf0, kt1 -> buf1 (8 GLDS/wave)
    STAGE(0, 0); STAGE(1, 1);
    VMCNT(4);          // kt0's 4 landed; kt1's 4 in flight
    BARRIER;

    #pragma unroll 2
    for (int kt = 0; kt < NKT; ++kt) {
        int bf = kt & 1;
        RDALL(bf);
        BARRIER;                               // all waves' reads done
        if (kt < NKT - 2) STAGE(bf, kt + 2);   // safe: after read-barrier
        MMALL;
        if (kt < NKT - 2)      { VMCNT(4); }   // kt+1 landed, kt+2 in flight
        else if (kt == NKT - 2){ VMCNT(0); }   // drain for last tile
        BARRIER;
    }

    // epilogue: C = acc + bias; lean fused chunk-sum S
    int crow0 = row0 + (w >> 1) * 64 + qg * 4;
    int ccol0 = col0 + (w & 1) * 64 + rl;
    int cg = (row0 + (w >> 1) * 64) >> 6;      // global chunk id (b*64+c)
    float aCol[4];
    if (WRITE_S && col0 < 512) {
        #pragma unroll
        for (int n = 0; n < 4; ++n) aCol[n] = Av[ccol0 + n * 16];  // hoisted
    }
    #pragma unroll
    for (int n = 0; n < 4; ++n) {
        int col = ccol0 + n * 16;
        float bv = bias[col];
        float v[4][4];
        #pragma unroll
        for (int i = 0; i < 4; ++i) {
            #pragma unroll
            for (int j = 0; j < 4; ++j) {
                v[i][j] = acc[i][n][j] + bv;
                size_t idx = (size_t)(crow0 + i * 16 + j) * NT + col;
                if (OUT_BF16)
                    ((__hip_bfloat16*)Cout)[idx] = __float2bfloat16(v[i][j]);
                else
                    ((float*)Cout)[idx] = v[i][j];
            }
        }
        if (WRITE_S && col0 < 512) {
            float a = aCol[n];
            float a2 = a * a, a4 = a2 * a2, a8 = a4 * a4, a16 = a8 * a8;
            float s = 0.f;
            #pragma unroll
            for (int i = 0; i < 4; ++i) {
                float u = ((v[i][0] * a + v[i][1]) * a + v[i][2]) * a + v[i][3];
                s = s * a16 + u;
            }
            float aq = (qg == 0) ? a8 * a4 : (qg == 1) ? a8 : (qg == 2) ? a4 : 1.0f;
            s *= aq;                            // s = sum_r v_r a^(63-r), partial over qg
            s += __shfl_xor(s, 16);
            s += __shfl_xor(s, 32);
            if (qg == 0) Sout[(size_t)cg * Hn + col] = s;
        }
    }
#undef GLDS
#undef STA
#undef STB
#undef STAGE
#undef BARRIER
#undef VMCNT
#undef RDALL
#undef MMALL
}

// ---------------------------------------------------------------- fused scan (carry + local scan + readout)
// BC layout: [row][1024] bf16, Bt = cols 0..511, Ct = cols 512..1023
__global__ __launch_bounds__(256) void scan_kernel(
    const __hip_bfloat16* __restrict__ BC, const float* __restrict__ Av,
    const float* __restrict__ S, __hip_bfloat16* __restrict__ Y)
{
    int blk = blockIdx.x;                       // 1024 = c*16 + half*8 + b
    int b = blk & 7;
    int half = (blk >> 3) & 1;
    int c = blk >> 4;
    int hh = half * 256 + threadIdx.x;
    float a = Av[hh];
    float aG = a;
    #pragma unroll
    for (int i = 0; i < 6; ++i) aG *= aG;       // a^64
    // carry: h entering chunk c = Horner over S[b, 0..c-1, hh]
    float h = 0.f;
    const float* Sp = S + (size_t)b * NCHUNK * Hn + hh;
    for (int cc = 0; cc < c; ++cc)
        h = aG * h + Sp[(size_t)cc * Hn];
    // local scan + readout
    const __hip_bfloat16* p = BC + ((size_t)(b * Ln + c * CHUNK) * 1024) + hh;
    __hip_bfloat16* yp = Y + ((size_t)(b * Ln + c * CHUNK) * Hn) + hh;
    #pragma unroll 8
    for (int i = 0; i < CHUNK; ++i) {
        float bv = __bfloat162float(p[(size_t)i * 1024]);
        float cv = __bfloat162float(p[(size_t)i * 1024 + 512]);
        h = a * h + bv;
        yp[(size_t)i * Hn] = __float2bfloat16(cv * h);
    }
}

// ---------------------------------------------------------------- launch
extern "C" void kernel_launch(void* const* d_in, const int* in_sizes, int n_in,
                              void* d_out, int out_size, void* d_ws, size_t ws_size,
                              hipStream_t stream)
{
    const float* x     = (const float*)d_in[0];
    const float* ln_g  = (const float*)d_in[1];
    const float* ln_b  = (const float*)d_in[2];
    const float* W_B   = (const float*)d_in[3];
    const float* b_B   = (const float*)d_in[4];
    const float* W_C   = (const float*)d_in[5];
    const float* b_C   = (const float*)d_in[6];
    const float* W_out = (const float*)d_in[7];
    const float* b_out = (const float*)d_in[8];
    const float* Avec  = (const float*)d_in[9];

    char* ws = (char*)d_ws;
    __hip_bfloat16* WbcT = (__hip_bfloat16*)(ws);                        // 1 MB
    __hip_bfloat16* WoT  = (__hip_bfloat16*)(ws + (1u << 20));           // 0.5 MB
    float*          bbc  = (float*)(ws + (1u << 20) + (1u << 19));       // 4 KB
    __hip_bfloat16* XN   = (__hip_bfloat16*)(ws + (2u << 20));           // 32 MB
    __hip_bfloat16* BC   = (__hip_bfloat16*)(ws + (34u << 20));          // 64 MB
    float*          Sbuf = (float*)(ws + (98u << 20));                   // 1 MB
    __hip_bfloat16* Y    = (__hip_bfloat16*)(ws + (100u << 20));         // 32 MB

    hipFuncSetAttribute((const void*)gemm32_kernel<1024, true, true>,
                        hipFuncAttributeMaxDynamicSharedMemorySize, 32768);
    hipFuncSetAttribute((const void*)gemm32_kernel<512, false, false>,
                        hipFuncAttributeMaxDynamicSharedMemorySize, 32768);

    pre_kernel<<<LNBLK + 2048, 256, 0, stream>>>(
        x, ln_g, ln_b, W_B, W_C, W_out, b_B, b_C, XN, WbcT, WoT, bbc);
    gemm32_kernel<1024, true, true><<<(Mrows / 128) * (1024 / 128), 256, 32768, stream>>>(
        XN, WbcT, bbc, BC, Avec, Sbuf);
    scan_kernel<<<Bn * NCHUNK * 2, 256, 0, stream>>>(BC, Avec, Sbuf, Y);
    gemm32_kernel<512, false, false><<<(Mrows / 128) * (512 / 128), 256, 32768, stream>>>(
        Y, WoT, b_out, d_out, nullptr, nullptr);
}